// Round 8
// baseline (133.709 us; speedup 1.0000x reference)
//
#include <hip/hip_runtime.h>

// Net_3152505995417: tiny GNN forward (N=116, E=6670, HID=64, EDIM=5).
// R9: ONE plain dispatch, 29 blocks (one per CU, co-resident), hand-rolled
// magic-flag barriers between phases (syncthreads -> threadfence(release) ->
// flag store; wave0 polls 29 flags relaxed + s_sleep; acquire fence after).
// Rationale: boundary cost ~5-10us x3 in R8's 4-dispatch chain (116.7us);
// cg::grid.sync was 14us/barrier (R1); flag barrier est 2-4us. Phase code is
// R0/R8-verified verbatim; work partition keeps full parallelism (no 29x
// redundant edge work -- the R3/R6 mistake). Pool uses per-block partials
// (Ppart[29][64]) + block-0 sum: no atomics, no init needed anywhere.
// Flags live in re-poisoned workspace (1 fill/iter confirmed in profiles):
// no stale state across iterations; poison==magic would fail absmax (caught).

#define NN   116
#define EE   6670
#define HID  64
#define EDIM 5
#define OUTD 4
#define ENC  122
#define EPSF 1e-10f
#define NH   (NN*HID)   // 7424
#define NB   29         // blocks

__device__ __forceinline__ int eid_ij(int i, int j) {
    int a = i < j ? i : j;
    int b = i < j ? j : i;
    return a*NN - ((a*(a+1)) >> 1) + (b - a - 1);   // triu k=1 row-major
}

__device__ __forceinline__ unsigned long long bar_magic(int phase) {
    return 0x9E3779B97F4A7C15ULL ^ ((unsigned long long)(phase + 1) * 0xC2B2AE3D27D4EB4FULL);
}

// release: all block writes visible device-wide before flag; acquire on exit.
__device__ __forceinline__ void flag_barrier(unsigned long long* flags, int phase,
                                             int bid, int tid, bool wait) {
    __syncthreads();                               // all lanes done, vmcnt drained
    const unsigned long long magic = bar_magic(phase);
    if (tid == 0) {
        __threadfence();                           // device-scope release (R8-proven path)
        __hip_atomic_store(&flags[phase*32 + bid], magic,
                           __ATOMIC_RELEASE, __HIP_MEMORY_SCOPE_AGENT);
    }
    if (wait) {
        if (tid < NB) {
            while (__hip_atomic_load(&flags[phase*32 + tid],
                                     __ATOMIC_RELAXED, __HIP_MEMORY_SCOPE_AGENT) != magic)
                __builtin_amdgcn_s_sleep(2);
        }
        __syncthreads();
        __threadfence();                           // acquire: fresh reads of peers' data
    }
}

__global__ __launch_bounds__(256) void fusedX(
    const float* __restrict__ enc, const float* __restrict__ ea,
    const float* __restrict__ W_enc, const float* __restrict__ b_enc,
    const float* __restrict__ W1, const float* __restrict__ b1,
    const float* __restrict__ p1, const float* __restrict__ We,
    const float* __restrict__ be, const float* __restrict__ pe,
    const float* __restrict__ W2, const float* __restrict__ b2,
    const float* __restrict__ p2, const float* __restrict__ Wl,
    const float* __restrict__ bl,
    float* __restrict__ Y1, float* __restrict__ Y2, float* __restrict__ d1,
    float* __restrict__ G, float* __restrict__ dv, float* __restrict__ S,
    float* __restrict__ Ppart, unsigned long long* __restrict__ flags,
    float* __restrict__ out)
{
    // one LDS arena, phase-aliased (max user: phase B = 14350 floats)
    __shared__ __align__(16) float smem[14352];    // 57408 B
    const int tid  = threadIdx.x;
    const int bid  = blockIdx.x;
    const int wid  = tid >> 6, lane = tid & 63;

    // ================= Phase A: X,Y1 (own 4 rows) + d1,G (1/29 edge slice) ======
    {
        float* sWe  = smem;            // ENC*HID = 7808
        float* sW1  = smem + 7808;     // HID*HID = 4096 (byte 31232, 16-al)
        float* sEnc = smem + 11904;    // 4*ENC   (byte 47616, 16-al)
        float* sX   = smem + 12392;
        {
            const float4* g4 = (const float4*)W_enc; float4* s4 = (float4*)sWe;
            for (int u = tid; u < ENC*HID/4; u += 256) s4[u] = g4[u];
        }
        {
            const float4* g4 = (const float4*)W1; float4* s4 = (float4*)sW1;
            for (int u = tid; u < HID*HID/4; u += 256) s4[u] = g4[u];
        }
        {
            const float4* g4 = (const float4*)(enc + bid*4*ENC);
            float4* s4 = (float4*)sEnc;
            for (int u = tid; u < 4*ENC/4; u += 256) s4[u] = g4[u];
        }
        __syncthreads();
        const int i = bid*4 + wid;
        float acc = b_enc[lane];
        const float* er = sEnc + wid*ENC;
        #pragma unroll 4
        for (int k = 0; k < ENC; ++k) acc = fmaf(er[k], sWe[k*HID + lane], acc);
        sX[wid*HID + lane] = acc;
        __syncthreads();
        float a2 = 0.f;
        const float* xr = sX + wid*HID;
        #pragma unroll 8
        for (int k = 0; k < HID; ++k) a2 = fmaf(xr[k], sW1[k*HID + lane], a2);
        Y1[i*HID + lane] = a2;
        // edge slice (grid-stride over 29 blocks), R0-verified inner code
        for (int u = bid*256 + tid; u < EE + EE*EDIM; u += NB*256) {
            if (u < EE) {
                const float* r = ea + u*EDIM;
                float a0 = 0.f;
                #pragma unroll
                for (int k = 0; k < EDIM; ++k) a0 = fmaf(r[k], p1[k], a0);
                d1[u] = a0;
            } else {
                const int idx = u - EE;
                const int e = idx / EDIM, k = idx - e*EDIM;
                const float* r = ea + e*EDIM;
                float a0 = 0.f;
                #pragma unroll
                for (int m = 0; m < EDIM; ++m) a0 = fmaf(fmaxf(r[m], 0.f), We[m*EDIM + k], a0);
                G[idx] = a0;
            }
        }
    }
    flag_barrier(flags, 0, bid, tid, true);

    // ================= Phase B: x2 = relu(D1@Y1+b1); dv; Y2 = x2@W2 ============
    {
        float* sY  = smem;            // NH
        float* sD  = smem + NH;       // EE (byte 29696, 8-al for float2)
        float* sX2 = smem + 14094;
        {
            const float4* g4 = (const float4*)Y1; float4* s4 = (float4*)sY;
            for (int u = tid; u < NH/4; u += 256) s4[u] = g4[u];
            const float2* g2 = (const float2*)d1; float2* s2 = (float2*)sD;
            for (int u = tid; u < EE/2; u += 256) s2[u] = g2[u];
        }
        __syncthreads();
        const int i = bid*4 + wid;
        float acc = b1[lane];
        #pragma unroll 4
        for (int j = 0; j < NN; ++j) {
            int jj = (j == i) ? (j ^ 1) : j;
            float wgt = (j == i) ? 0.f : sD[eid_ij(i, jj)];
            acc = fmaf(wgt, sY[jj*HID + lane], acc);
        }
        float v = fmaxf(acc, 0.f);
        float r = v * pe[lane];
        #pragma unroll
        for (int off = 32; off > 0; off >>= 1) r += __shfl_down(r, off, 64);
        if (lane == 0) dv[i] = r;
        sX2[wid*HID + lane] = v;
        __syncthreads();
        float a2 = 0.f;
        const float* xr = sX2 + wid*HID;
        #pragma unroll 8
        for (int k = 0; k < HID; ++k) a2 = fmaf(xr[k], W2[k*HID + lane], a2);
        Y2[i*HID + lane] = a2;
    }
    flag_barrier(flags, 1, bid, tid, true);

    // ================= Phase C: S gather (580 units = 29 blk x 4 waves x 5) ====
    float* sDv = smem + 8004;          // persists through D/E
    if (tid < NN) sDv[tid] = dv[tid];
    __syncthreads();
    {
        #pragma unroll
        for (int r5 = 0; r5 < 5; ++r5) {
            const int wg = bid*4 + wid + 116*r5;   // bijection onto [0,580)
            const int i = wg / EDIM, k = wg - i*EDIM;
            const float di = sDv[i];
            float acc = 0.f;
            #pragma unroll
            for (int rep = 0; rep < 2; ++rep) {
                int j = lane + rep*64;
                if (j < NN && j != i) {
                    float cm = fmaxf(fmaxf(di, sDv[j]), 0.f) + EPSF;
                    acc += G[eid_ij(i, j)*EDIM + k] / cm;
                }
            }
            #pragma unroll
            for (int off = 32; off > 0; off >>= 1) acc += __shfl_down(acc, off, 64);
            if (lane == 0) S[wg] = acc;
        }
    }
    flag_barrier(flags, 2, bid, tid, true);

    // ================= Phase D: d2 own 4 rows;  E: x3 + partial pool ===========
    {
        float* sY  = smem;            // Y2 tile
        float* sS  = smem + NH;       // 580
        float* sD2 = smem + 8124;     // 464
        float* sR  = smem + 8588;     // 256
        {
            const float4* g4 = (const float4*)Y2; float4* s4 = (float4*)sY;
            for (int u = tid; u < NH/4; u += 256) s4[u] = g4[u];
        }
        for (int u = tid; u < NN*EDIM; u += 256) sS[u] = S[u];
        __syncthreads();

        float ber[EDIM], p2r[EDIM];
        #pragma unroll
        for (int k = 0; k < EDIM; ++k) { ber[k] = be[k]; p2r[k] = p2[k]; }

        const int i = bid*4 + wid;
        #pragma unroll
        for (int rep = 0; rep < 2; ++rep) {
            const int j = lane + rep*64;
            if (j < NN) {
                float val = 0.f;
                if (j != i) {
                    const int a = i < j ? i : j, b = i < j ? j : i;
                    const int e = a*NN - ((a*(a+1)) >> 1) + (b - a - 1);
                    const float da = sDv[a], db = sDv[b];
                    const float rc = 1.f / (fmaxf(fmaxf(da, db), 0.f) + EPSF);
                    #pragma unroll
                    for (int k = 0; k < EDIM; ++k) {
                        const float gp = G[e*EDIM + k] * rc;
                        const float v = fmaf(da, sS[a*EDIM + k] - gp,
                                       fmaf(db, sS[b*EDIM + k] - gp, ber[k]));
                        val = fmaf(fmaxf(v, 0.f), p2r[k], val);
                    }
                }
                sD2[wid*NN + j] = val;
            }
        }
        __syncthreads();

        float acc = b2[lane];
        const float* d2r = sD2 + wid*NN;
        #pragma unroll 4
        for (int j = 0; j < NN; ++j)
            acc = fmaf(d2r[j], sY[j*HID + lane], acc);
        sR[wid*HID + lane] = acc;
        __syncthreads();
        if (wid == 0)
            Ppart[bid*HID + lane] = sR[lane] + sR[HID + lane] + sR[2*HID + lane] + sR[3*HID + lane];
    }
    flag_barrier(flags, 3, bid, tid, bid == 0);    // only block 0 waits

    // ================= Phase F (block 0): out = (mean Ppart)@Wl + bl ===========
    if (bid == 0 && wid == 0) {
        float psum = 0.f;
        #pragma unroll 4
        for (int b = 0; b < NB; ++b) psum += Ppart[b*HID + lane];
        const float val = psum * (1.0f / NN);
        float res[OUTD];
        #pragma unroll
        for (int o = 0; o < OUTD; ++o) {
            float r = val * Wl[lane*OUTD + o];
            #pragma unroll
            for (int off = 32; off > 0; off >>= 1) r += __shfl_xor(r, off, 64);
            res[o] = r;
        }
        if (lane < OUTD) out[lane] = res[lane] + bl[lane];
    }
}

extern "C" void kernel_launch(void* const* d_in, const int* in_sizes, int n_in,
                              void* d_out, int out_size, void* d_ws, size_t ws_size,
                              hipStream_t stream)
{
    const float* enc   = (const float*)d_in[0];
    const float* ea    = (const float*)d_in[1];
    const float* W_enc = (const float*)d_in[3];
    const float* b_enc = (const float*)d_in[4];
    const float* W1    = (const float*)d_in[5];
    const float* b1    = (const float*)d_in[6];
    const float* p1    = (const float*)d_in[7];
    const float* We    = (const float*)d_in[8];
    const float* be    = (const float*)d_in[9];
    const float* pe    = (const float*)d_in[10];
    const float* W2    = (const float*)d_in[11];
    const float* b2    = (const float*)d_in[12];
    const float* p2    = (const float*)d_in[13];
    const float* Wl    = (const float*)d_in[14];
    const float* bl    = (const float*)d_in[15];
    float* ws = (float*)d_ws;

    // Workspace (floats):
    float* Y1 = ws;                    // [7424]
    float* Y2 = ws + NH;               // [7424]
    float* d1 = ws + 2*NH;             // [6670]
    float* G  = d1 + EE;               // [33350]
    float* dv = G + EE*EDIM;           // [116]
    float* S  = dv + NN;               // [580]
    float* Pp = S + NN*EDIM;           // [29*64]
    unsigned long long* flags = (unsigned long long*)(ws + 57424); // byte 229696, 8-al; [4*32]
    float* out = (float*)d_out;

    fusedX<<<NB, 256, 0, stream>>>(enc, ea, W_enc, b_enc, W1, b1, p1, We, be, pe,
                                   W2, b2, p2, Wl, bl,
                                   Y1, Y2, d1, G, dv, S, Pp, flags, out);
}